// Round 1
// baseline (872.736 us; speedup 1.0000x reference)
//
#include <hip/hip_runtime.h>
#include <cstdint>
#include <cstddef>

// CA3RecurrentAttractor — key semantic facts (proven from the reference):
//  * (v >= 30) is false after init and after every step (spikes reset to -55,
//    non-spikers stay < 30, clip(.,-90,30) cannot create 30 from below), so
//    recurrent_current == 0 always -> W_rec (d_in[2]) is unused.
//  * Output = spike indicator of step 5 only, a pure per-element function of
//    I = 10 * (dg @ W_mossy.T), with uniform v0=-65, u0=-13.
//  * dg is exactly {0,1}: sparse gather-sum over set bits == dense in-order
//    fp32 dot (adding exact zeros is a no-op) -> fp32 precision parity.

constexpr int Bn   = 16384;
constexpr int Gn   = 2048;
constexpr int Nn   = 512;
constexpr int ROWS = 32;          // batch rows per block
constexpr int TG   = 16;          // g-tile width staged in LDS
constexpr int NCHUNK = Gn / 32;   // 64 u32 bitmask chunks per row

__launch_bounds__(512, 2)
__global__ void ca3_sparse_kernel(const float* __restrict__ dg,
                                  const float* __restrict__ Wm,
                                  const float* __restrict__ v0,
                                  const float* __restrict__ u0,
                                  float* __restrict__ out) {
#pragma clang fp contract(off)
  __shared__ float    lds_w[TG * Nn];          // 32 KB, [g][n]
  __shared__ uint32_t lds_bits[ROWS][NCHUNK];  //  8 KB

  const int t    = (int)threadIdx.x;    // 0..511, thread = output column n
  const int row0 = (int)blockIdx.x * ROWS;

  // ---- Phase 1: build dg bitmasks for our 32 rows --------------------------
  {
    const int r  = t >> 4;          // 32 rows, 16 threads each
    const int c0 = (t & 15) * 4;    // 4 chunks of 32 bits per thread
    const float* p = dg + (size_t)(row0 + r) * Gn + (size_t)c0 * 32;
#pragma unroll
    for (int cc = 0; cc < 4; ++cc) {
      uint32_t bits = 0;
#pragma unroll
      for (int i = 0; i < 8; ++i) {
        float4 x = reinterpret_cast<const float4*>(p + cc * 32)[i];
        bits |= (x.x != 0.0f ? 1u : 0u) << (i * 4 + 0);
        bits |= (x.y != 0.0f ? 1u : 0u) << (i * 4 + 1);
        bits |= (x.z != 0.0f ? 1u : 0u) << (i * 4 + 2);
        bits |= (x.w != 0.0f ? 1u : 0u) << (i * 4 + 3);
      }
      lds_bits[r][c0 + cc] = bits;
    }
  }

  float acc[ROWS];
#pragma unroll
  for (int r = 0; r < ROWS; ++r) acc[r] = 0.0f;

  // ---- Main loop over g-tiles ---------------------------------------------
  for (int gt = 0; gt < Gn / TG; ++gt) {
    __syncthreads();   // prev-tile reads done (and phase-1 bits visible)
    {
      // Stage W[n][gt*16 .. +16) -> lds_w[g][n].
      // thread t: k=t&3 picks float4 within the 16-wide row slice,
      // n = pass*128 + t>>2. Wave reads 8 contiguous 128B chunks per instr.
      const int k  = t & 3;
      const int nb = t >> 2;
#pragma unroll
      for (int pq = 0; pq < 4; ++pq) {
        const int n = pq * 128 + nb;
        const float4 w4 = *reinterpret_cast<const float4*>(
            Wm + (size_t)n * Gn + gt * TG + k * 4);
        lds_w[(k * 4 + 0) * Nn + n] = w4.x;
        lds_w[(k * 4 + 1) * Nn + n] = w4.y;
        lds_w[(k * 4 + 2) * Nn + n] = w4.z;
        lds_w[(k * 4 + 3) * Nn + n] = w4.w;
      }
    }
    __syncthreads();

    const int shift = (gt & 1) * 16;
#pragma unroll
    for (int r = 0; r < ROWS; ++r) {
      uint32_t b = (lds_bits[r][gt >> 1] >> shift) & 0xFFFFu;
      // Uniform across the block -> force scalar loop control (SALU).
      b = __builtin_amdgcn_readfirstlane(b);
      while (b) {
        // Unroll x4: keep 4 ds_reads in flight per latency window.
        // b & (b-1) is safe at b==0; |0x8000 makes ctz of an empty mask
        // yield a safe in-range dummy index (bit 15 < TG), selected away.
        const int g0 = __builtin_ctz(b);
        const uint32_t b1 = b & (b - 1);
        const int g1 = __builtin_ctz(b1 | 0x8000u);
        const uint32_t b2 = b1 & (b1 - 1);
        const int g2 = __builtin_ctz(b2 | 0x8000u);
        const uint32_t b3 = b2 & (b2 - 1);
        const int g3 = __builtin_ctz(b3 | 0x8000u);

        float x0 = lds_w[g0 * Nn + t];
        float x1 = lds_w[g1 * Nn + t];
        float x2 = lds_w[g2 * Nn + t];
        float x3 = lds_w[g3 * Nn + t];
        x1 = (b1 != 0u) ? x1 : 0.0f;
        x2 = (b2 != 0u) ? x2 : 0.0f;
        x3 = (b3 != 0u) ? x3 : 0.0f;

        // Sequential adds preserve in-order dot-product semantics
        // (the masked-off terms add an exact 0.0f).
        acc[r] += x0;
        acc[r] += x1;
        acc[r] += x2;
        acc[r] += x3;

        b = b3 & (b3 - 1);
      }
    }
  }

  // ---- Epilogue: 5 Izhikevich Euler steps (FMA contraction OFF above) -----
  const float vi = v0[t];
  const float ui = u0[t];
#pragma unroll
  for (int r = 0; r < ROWS; ++r) {
    const float I = acc[r] * 10.0f;
    float v = vi, u = ui, spk = 0.0f;
#pragma unroll
    for (int s = 0; s < 5; ++s) {
      const float dv = 0.04f * v * v + 5.0f * v + 140.0f - u + I;
      const float du = 0.02f * (0.2f * v - u);
      v = v + dv * 0.5f;
      u = u + du * 0.5f;
      spk = (v >= 30.0f) ? 1.0f : 0.0f;
      if (spk > 0.0f) v = -55.0f;
      u = u + spk * 4.0f;
      v = fminf(fmaxf(v, -90.0f), 30.0f);
    }
    out[(size_t)(row0 + r) * Nn + t] = spk;
  }
}

extern "C" void kernel_launch(void* const* d_in, const int* in_sizes, int n_in,
                              void* d_out, int out_size, void* d_ws, size_t ws_size,
                              hipStream_t stream) {
  const float* dg = (const float*)d_in[0];   // [B, G]
  const float* Wm = (const float*)d_in[1];   // [N, G]
  // d_in[2] = W_rec [N, N]: provably unused (recurrent spikes always zero).
  const float* v0 = (const float*)d_in[3];   // [N]
  const float* u0 = (const float*)d_in[4];   // [N]
  float* out = (float*)d_out;                // [B, N] spikes (fp32 0/1)

  dim3 grid(Bn / ROWS);   // 512 blocks
  dim3 block(512);
  hipLaunchKernelGGL(ca3_sparse_kernel, grid, block, 0, stream,
                     dg, Wm, v0, u0, out);
}

// Round 2
// 132.482 us; speedup vs baseline: 6.5876x; 6.5876x over previous
//
#include <hip/hip_runtime.h>
#include <cstdint>
#include <cstddef>

// CA3RecurrentAttractor — proven semantics (round 1 passed absmax 0):
//  * recurrent term is always zero -> W_rec (d_in[2]) unused.
//  * out = izhikevich5(10 * (dg @ W_mossy.T)) elementwise, v0=-65, u0=-13.
// This round: MFMA path. W split EXACTLY into 3 bf16 planes (w = h0+h1+h2,
// splits exact in fp32), dg -> bf16 exact {0,1}. One fp32 accumulator chain,
// 3 MFMAs per (frag, K-step). Error vs np ref ~2e-6 in I units — same level
// as the in-order-vs-BLAS perturbation already shown to flip zero spikes.

typedef __attribute__((ext_vector_type(8))) short bf16x8;
typedef __attribute__((ext_vector_type(8))) unsigned short u16x8;
typedef __attribute__((ext_vector_type(4))) float f32x4;
typedef __attribute__((ext_vector_type(4))) unsigned int u32x4;

constexpr int Bn = 16384, Gn = 2048, Nn = 512;
constexpr int BM = 128, BN = 128, BK = 32;
constexpr int NKT = Gn / BK;  // 64
// ws layout: A_bf16 [kt][s(4)][m(16384)][16B]  then  B_bf16 [kt][p(3)][s(4)][n(512)][16B]
constexpr size_t A_BYTES = (size_t)NKT * 4 * Bn * 16;      // 64 MiB
constexpr size_t B_BYTES = (size_t)NKT * 3 * 4 * Nn * 16;  // 6 MiB

__device__ __forceinline__ unsigned short f2bf(float x) {  // RNE float->bf16
  uint32_t u = __builtin_bit_cast(uint32_t, x);
  u += 0x7FFFu + ((u >> 16) & 1u);
  return (unsigned short)(u >> 16);
}
__device__ __forceinline__ float bf2f(unsigned short h) {
  return __builtin_bit_cast(float, (uint32_t)h << 16);
}

__device__ __forceinline__ void glds16(const void* g, const void* l) {
  __builtin_amdgcn_global_load_lds(
      (const __attribute__((address_space(1))) unsigned int*)g,
      (__attribute__((address_space(3))) unsigned int*)l, 16, 0, 0);
}

__device__ __forceinline__ float izhi5(float I, float vi, float ui) {
#pragma clang fp contract(off)
  float v = vi, u = ui, spk = 0.0f;
#pragma unroll
  for (int st = 0; st < 5; ++st) {
    float dv = 0.04f * v * v + 5.0f * v + 140.0f - u + I;
    float du = 0.02f * (0.2f * v - u);
    v = v + dv * 0.5f;
    u = u + du * 0.5f;
    spk = (v >= 30.0f) ? 1.0f : 0.0f;
    if (spk > 0.0f) v = -55.0f;
    u = u + spk * 4.0f;
    v = fminf(fmaxf(v, -90.0f), 30.0f);
  }
  return spk;
}

// ---- Preprocess dg: fp32 [B][G] -> bf16 blocked [kt][s][m][8 bf16] ---------
__launch_bounds__(256)
__global__ void prep_dg(const float* __restrict__ dg, unsigned short* __restrict__ Ab) {
  __shared__ uint32_t lds[64][129];  // 64 m x 128 u32 (256 bf16), +1 pad
  const int t  = (int)threadIdx.x;
  const int mt = (int)blockIdx.x >> 3;  // 256 m-tiles of 64
  const int gt = (int)blockIdx.x & 7;   // 8 g-tiles of 256
  const int m0 = mt * 64, g0 = gt * 256;
  {
    const int mm = t >> 2, q = t & 3;
    const float* src = dg + (size_t)(m0 + mm) * Gn + g0;
#pragma unroll
    for (int i = 0; i < 16; ++i) {
      float4 v = *reinterpret_cast<const float4*>(src + i * 16 + q * 4);
      uint32_t a = (v.x != 0.0f ? 0x3F80u : 0u) | (v.y != 0.0f ? 0x3F800000u : 0u);
      uint32_t b = (v.z != 0.0f ? 0x3F80u : 0u) | (v.w != 0.0f ? 0x3F800000u : 0u);
      const int c = i * 8 + q * 2;
      lds[mm][c] = a; lds[mm][c + 1] = b;
    }
  }
  __syncthreads();
  {
    const int mm = t & 63, c0 = t >> 6;
#pragma unroll
    for (int cc = 0; cc < 8; ++cc) {
      const int c = c0 + cc * 4;        // chunk 0..31
      const int ktl = c >> 2, s = c & 3;
      const int cb = ktl * 16 + s * 4;
      u32x4 v;
      v.x = lds[mm][cb + 0]; v.y = lds[mm][cb + 1];
      v.z = lds[mm][cb + 2]; v.w = lds[mm][cb + 3];
      const size_t off = ((size_t)((gt * 8 + ktl) * 4 + s) * Bn + (m0 + mm)) * 16;
      *reinterpret_cast<u32x4*>(reinterpret_cast<char*>(Ab) + off) = v;
    }
  }
}

// ---- Preprocess W: fp32 [N][G] -> 3 bf16 planes blocked [kt][p][s][n][8] ---
__launch_bounds__(256)
__global__ void prep_W(const float* __restrict__ Wm, unsigned short* __restrict__ Bb) {
  const int n  = (int)blockIdx.x;   // 512
  const int gi = (int)threadIdx.x;  // 256 groups of 8 g
  const float* src = Wm + (size_t)n * Gn + gi * 8;
  u16x8 h0, h1, h2;
#pragma unroll
  for (int e = 0; e < 8; ++e) {
    const float w  = src[e];
    const unsigned short b0 = f2bf(w);  const float f0 = bf2f(b0);
    const float r1 = w - f0;            // exact
    const unsigned short b1 = f2bf(r1); const float f1 = bf2f(b1);
    const float r2 = r1 - f1;           // exact
    const unsigned short b2 = f2bf(r2);
    h0[e] = b0; h1[e] = b1; h2[e] = b2;
  }
  const int kt = gi >> 2, s = gi & 3;
  char* base = reinterpret_cast<char*>(Bb);
  *reinterpret_cast<u16x8*>(base + ((size_t)((kt * 3 + 0) * 4 + s) * Nn + n) * 16) = h0;
  *reinterpret_cast<u16x8*>(base + ((size_t)((kt * 3 + 1) * 4 + s) * Nn + n) * 16) = h1;
  *reinterpret_cast<u16x8*>(base + ((size_t)((kt * 3 + 2) * 4 + s) * Nn + n) * 16) = h2;
}

// ---- Main GEMM + Izhikevich epilogue (m97-style 128x128, BK=32) -----------
__launch_bounds__(256, 2)
__global__ void gemm_spike(const char* __restrict__ Ab, const char* __restrict__ Bb,
                           const float* __restrict__ v0, const float* __restrict__ u0,
                           float* __restrict__ out) {
  __shared__ __align__(16) char lds[32768];  // A: [s(4)][m(128)][16] @0 ; B: [p(3)][s(4)][n(128)][16] @8192
  const int t  = (int)threadIdx.x;
  const int bx = (int)blockIdx.x;       // 512 = 128 m-tiles x 4 n-tiles
  const int mt = bx >> 2, nt = bx & 3;
  const int m0 = mt * BM, n0 = nt * BN;

  // staging source offsets (within current kt slab)
  uint32_t asrc[2], bsrc[6];
#pragma unroll
  for (int c = 0; c < 2; ++c) {
    const int j = t + 256 * c;          // 0..511 : s=j>>7, i=j&127
    asrc[c] = (uint32_t)((((j >> 7) * Bn) + m0 + (j & 127)) * 16);
  }
#pragma unroll
  for (int c = 0; c < 6; ++c) {
    const int j = t + 256 * c;          // 0..1535 : p=j>>9, s=(j>>7)&3, i=j&127
    bsrc[c] = (uint32_t)(((((j >> 9) * 4 + ((j >> 7) & 3)) * Nn) + n0 + (j & 127)) * 16);
  }

  const int l  = t & 63, wv = t >> 6;
  const int wr = wv >> 1, wc = wv & 1;  // wave grid 2(M) x 2(N), wave tile 64x64
  const int lr = l & 15, kh = l >> 4;

  uint32_t aoff[4], boff[3][4];
#pragma unroll
  for (int mf = 0; mf < 4; ++mf)
    aoff[mf] = (uint32_t)(((kh * 128) + wr * 64 + mf * 16 + lr) * 16);
#pragma unroll
  for (int p = 0; p < 3; ++p)
#pragma unroll
    for (int nf = 0; nf < 4; ++nf)
      boff[p][nf] = (uint32_t)(8192 + (((p * 4 + kh) * 128) + wc * 64 + nf * 16 + lr) * 16);

  f32x4 acc[4][4];
#pragma unroll
  for (int i = 0; i < 4; ++i)
#pragma unroll
    for (int j = 0; j < 4; ++j)
      acc[i][j] = (f32x4){0.0f, 0.0f, 0.0f, 0.0f};

  const char* pa = Ab;
  const char* pb = Bb;
  for (int kt = 0; kt < NKT; ++kt) {
    __syncthreads();
#pragma unroll
    for (int c = 0; c < 2; ++c) glds16(pa + asrc[c], &lds[(t + 256 * c) * 16]);
#pragma unroll
    for (int c = 0; c < 6; ++c) glds16(pb + bsrc[c], &lds[8192 + (t + 256 * c) * 16]);
    pa += (size_t)4 * Bn * 16;      // 1 MiB
    pb += (size_t)12 * Nn * 16;     // 96 KiB
    __syncthreads();                // drains vmcnt -> staged data visible

    bf16x8 af[4], bfr[3][4];
#pragma unroll
    for (int mf = 0; mf < 4; ++mf)
      af[mf] = *reinterpret_cast<const bf16x8*>(&lds[aoff[mf]]);
#pragma unroll
    for (int p = 0; p < 3; ++p)
#pragma unroll
      for (int nf = 0; nf < 4; ++nf)
        bfr[p][nf] = *reinterpret_cast<const bf16x8*>(&lds[boff[p][nf]]);
#pragma unroll
    for (int p = 0; p < 3; ++p)
#pragma unroll
      for (int mf = 0; mf < 4; ++mf)
#pragma unroll
        for (int nf = 0; nf < 4; ++nf)
          acc[mf][nf] = __builtin_amdgcn_mfma_f32_16x16x32_bf16(
              af[mf], bfr[p][nf], acc[mf][nf], 0, 0, 0);
  }

  // epilogue: C/D layout (16x16): col = lane&15, row = (lane>>4)*4 + reg
#pragma unroll
  for (int nf = 0; nf < 4; ++nf) {
    const int ncol = n0 + wc * 64 + nf * 16 + lr;
    const float vi = v0[ncol], ui = u0[ncol];
#pragma unroll
    for (int mf = 0; mf < 4; ++mf) {
      const int mrow = m0 + wr * 64 + mf * 16 + kh * 4;
#pragma unroll
      for (int r = 0; r < 4; ++r) {
        const float I = acc[mf][nf][r] * 10.0f;
        out[(size_t)(mrow + r) * Nn + ncol] = izhi5(I, vi, ui);
      }
    }
  }
}

// ---- Fallback (round-1 exact sparse kernel) if ws too small ---------------
constexpr int ROWS = 32, TG = 16, NCHUNK = Gn / 32;

__launch_bounds__(512, 2)
__global__ void ca3_sparse_kernel(const float* __restrict__ dg,
                                  const float* __restrict__ Wm,
                                  const float* __restrict__ v0,
                                  const float* __restrict__ u0,
                                  float* __restrict__ out) {
#pragma clang fp contract(off)
  __shared__ float    lds_w[TG * Nn];
  __shared__ uint32_t lds_bits[ROWS][NCHUNK];
  const int t    = (int)threadIdx.x;
  const int row0 = (int)blockIdx.x * ROWS;
  {
    const int r  = t >> 4;
    const int c0 = (t & 15) * 4;
    const float* p = dg + (size_t)(row0 + r) * Gn + (size_t)c0 * 32;
#pragma unroll
    for (int cc = 0; cc < 4; ++cc) {
      uint32_t bits = 0;
#pragma unroll
      for (int i = 0; i < 8; ++i) {
        float4 x = reinterpret_cast<const float4*>(p + cc * 32)[i];
        bits |= (x.x != 0.0f ? 1u : 0u) << (i * 4 + 0);
        bits |= (x.y != 0.0f ? 1u : 0u) << (i * 4 + 1);
        bits |= (x.z != 0.0f ? 1u : 0u) << (i * 4 + 2);
        bits |= (x.w != 0.0f ? 1u : 0u) << (i * 4 + 3);
      }
      lds_bits[r][c0 + cc] = bits;
    }
  }
  float acc[ROWS];
#pragma unroll
  for (int r = 0; r < ROWS; ++r) acc[r] = 0.0f;
  for (int gt = 0; gt < Gn / TG; ++gt) {
    __syncthreads();
    {
      const int k  = t & 3;
      const int nb = t >> 2;
#pragma unroll
      for (int pq = 0; pq < 4; ++pq) {
        const int n = pq * 128 + nb;
        const float4 w4 = *reinterpret_cast<const float4*>(
            Wm + (size_t)n * Gn + gt * TG + k * 4);
        lds_w[(k * 4 + 0) * Nn + n] = w4.x;
        lds_w[(k * 4 + 1) * Nn + n] = w4.y;
        lds_w[(k * 4 + 2) * Nn + n] = w4.z;
        lds_w[(k * 4 + 3) * Nn + n] = w4.w;
      }
    }
    __syncthreads();
    const int shift = (gt & 1) * 16;
#pragma unroll
    for (int r = 0; r < ROWS; ++r) {
      uint32_t b = (lds_bits[r][gt >> 1] >> shift) & 0xFFFFu;
      b = __builtin_amdgcn_readfirstlane(b);
      while (b) {
        const int g0 = __builtin_ctz(b);
        const uint32_t b1 = b & (b - 1);
        const int g1 = __builtin_ctz(b1 | 0x8000u);
        const uint32_t b2 = b1 & (b1 - 1);
        const int g2 = __builtin_ctz(b2 | 0x8000u);
        const uint32_t b3 = b2 & (b2 - 1);
        const int g3 = __builtin_ctz(b3 | 0x8000u);
        float x0 = lds_w[g0 * Nn + t];
        float x1 = lds_w[g1 * Nn + t];
        float x2 = lds_w[g2 * Nn + t];
        float x3 = lds_w[g3 * Nn + t];
        x1 = (b1 != 0u) ? x1 : 0.0f;
        x2 = (b2 != 0u) ? x2 : 0.0f;
        x3 = (b3 != 0u) ? x3 : 0.0f;
        acc[r] += x0; acc[r] += x1; acc[r] += x2; acc[r] += x3;
        b = b3 & (b3 - 1);
      }
    }
  }
  const float vi = v0[t];
  const float ui = u0[t];
#pragma unroll
  for (int r = 0; r < ROWS; ++r) {
    out[(size_t)(row0 + r) * Nn + t] = izhi5(acc[r] * 10.0f, vi, ui);
  }
}

extern "C" void kernel_launch(void* const* d_in, const int* in_sizes, int n_in,
                              void* d_out, int out_size, void* d_ws, size_t ws_size,
                              hipStream_t stream) {
  const float* dg = (const float*)d_in[0];
  const float* Wm = (const float*)d_in[1];
  const float* v0 = (const float*)d_in[3];
  const float* u0 = (const float*)d_in[4];
  float* out = (float*)d_out;

  if (ws_size < A_BYTES + B_BYTES) {
    hipLaunchKernelGGL(ca3_sparse_kernel, dim3(Bn / ROWS), dim3(512), 0, stream,
                       dg, Wm, v0, u0, out);
    return;
  }
  char* Ab = (char*)d_ws;
  char* Bb = (char*)d_ws + A_BYTES;
  hipLaunchKernelGGL(prep_dg, dim3(2048), dim3(256), 0, stream,
                     dg, (unsigned short*)Ab);
  hipLaunchKernelGGL(prep_W, dim3(512), dim3(256), 0, stream,
                     Wm, (unsigned short*)Bb);
  hipLaunchKernelGGL(gemm_spike, dim3(512), dim3(256), 0, stream,
                     Ab, Bb, v0, u0, out);
}

// Round 3
// 121.740 us; speedup vs baseline: 7.1688x; 1.0882x over previous
//
#include <hip/hip_runtime.h>
#include <cstdint>
#include <cstddef>

// CA3RecurrentAttractor — proven semantics (rounds 1-2 passed absmax 0):
//  * recurrent term is always zero -> W_rec (d_in[2]) unused.
//  * out = izhikevich5(10 * (dg @ W_mossy.T)) elementwise, v0=-65, u0=-13.
//  * W split EXACTLY into 3 bf16 planes (w = h0+h1+h2), dg -> bf16 exact.
// Round 3: minimum-2-phase double-buffered GEMM (stage next tile BEFORE
// computing current; ONE barrier per K-step) + bijective XCD swizzle so the
// 4 n-tile blocks sharing an A slab land on the same XCD L2.

typedef __attribute__((ext_vector_type(8))) short bf16x8;
typedef __attribute__((ext_vector_type(8))) unsigned short u16x8;
typedef __attribute__((ext_vector_type(4))) float f32x4;
typedef __attribute__((ext_vector_type(4))) unsigned int u32x4;

constexpr int Bn = 16384, Gn = 2048, Nn = 512;
constexpr int BM = 128, BN = 128, BK = 32;
constexpr int NKT = Gn / BK;  // 64
// ws layout: A_bf16 [kt][s(4)][m(16384)][16B]  then  B_bf16 [kt][p(3)][s(4)][n(512)][16B]
constexpr size_t SLAB_A = (size_t)4 * Bn * 16;      // 1 MiB per kt
constexpr size_t SLAB_B = (size_t)12 * Nn * 16;     // 96 KiB per kt
constexpr size_t A_BYTES = (size_t)NKT * SLAB_A;    // 64 MiB
constexpr size_t B_BYTES = (size_t)NKT * SLAB_B;    // 6 MiB

__device__ __forceinline__ unsigned short f2bf(float x) {  // RNE float->bf16
  uint32_t u = __builtin_bit_cast(uint32_t, x);
  u += 0x7FFFu + ((u >> 16) & 1u);
  return (unsigned short)(u >> 16);
}
__device__ __forceinline__ float bf2f(unsigned short h) {
  return __builtin_bit_cast(float, (uint32_t)h << 16);
}

__device__ __forceinline__ void glds16(const void* g, const void* l) {
  __builtin_amdgcn_global_load_lds(
      (const __attribute__((address_space(1))) unsigned int*)g,
      (__attribute__((address_space(3))) unsigned int*)l, 16, 0, 0);
}

__device__ __forceinline__ float izhi5(float I, float vi, float ui) {
#pragma clang fp contract(off)
  float v = vi, u = ui, spk = 0.0f;
#pragma unroll
  for (int st = 0; st < 5; ++st) {
    float dv = 0.04f * v * v + 5.0f * v + 140.0f - u + I;
    float du = 0.02f * (0.2f * v - u);
    v = v + dv * 0.5f;
    u = u + du * 0.5f;
    spk = (v >= 30.0f) ? 1.0f : 0.0f;
    if (spk > 0.0f) v = -55.0f;
    u = u + spk * 4.0f;
    v = fminf(fmaxf(v, -90.0f), 30.0f);
  }
  return spk;
}

// ---- Preprocess dg: fp32 [B][G] -> bf16 blocked [kt][s][m][8 bf16] ---------
__launch_bounds__(256)
__global__ void prep_dg(const float* __restrict__ dg, unsigned short* __restrict__ Ab) {
  __shared__ uint32_t lds[64][129];  // 64 m x 128 u32 (256 bf16), +1 pad
  const int t  = (int)threadIdx.x;
  const int mt = (int)blockIdx.x >> 3;  // 256 m-tiles of 64
  const int gt = (int)blockIdx.x & 7;   // 8 g-tiles of 256
  const int m0 = mt * 64, g0 = gt * 256;
  {
    const int mm = t >> 2, q = t & 3;
    const float* src = dg + (size_t)(m0 + mm) * Gn + g0;
#pragma unroll
    for (int i = 0; i < 16; ++i) {
      float4 v = *reinterpret_cast<const float4*>(src + i * 16 + q * 4);
      uint32_t a = (v.x != 0.0f ? 0x3F80u : 0u) | (v.y != 0.0f ? 0x3F800000u : 0u);
      uint32_t b = (v.z != 0.0f ? 0x3F80u : 0u) | (v.w != 0.0f ? 0x3F800000u : 0u);
      const int c = i * 8 + q * 2;
      lds[mm][c] = a; lds[mm][c + 1] = b;
    }
  }
  __syncthreads();
  {
    const int mm = t & 63, c0 = t >> 6;
#pragma unroll
    for (int cc = 0; cc < 8; ++cc) {
      const int c = c0 + cc * 4;        // chunk 0..31
      const int ktl = c >> 2, s = c & 3;
      const int cb = ktl * 16 + s * 4;
      u32x4 v;
      v.x = lds[mm][cb + 0]; v.y = lds[mm][cb + 1];
      v.z = lds[mm][cb + 2]; v.w = lds[mm][cb + 3];
      const size_t off = ((size_t)((gt * 8 + ktl) * 4 + s) * Bn + (m0 + mm)) * 16;
      *reinterpret_cast<u32x4*>(reinterpret_cast<char*>(Ab) + off) = v;
    }
  }
}

// ---- Preprocess W: fp32 [N][G] -> 3 bf16 planes blocked [kt][p][s][n][8] ---
__launch_bounds__(256)
__global__ void prep_W(const float* __restrict__ Wm, unsigned short* __restrict__ Bb) {
  const int n  = (int)blockIdx.x;   // 512
  const int gi = (int)threadIdx.x;  // 256 groups of 8 g
  const float* src = Wm + (size_t)n * Gn + gi * 8;
  u16x8 h0, h1, h2;
#pragma unroll
  for (int e = 0; e < 8; ++e) {
    const float w  = src[e];
    const unsigned short b0 = f2bf(w);  const float f0 = bf2f(b0);
    const float r1 = w - f0;            // exact
    const unsigned short b1 = f2bf(r1); const float f1 = bf2f(b1);
    const float r2 = r1 - f1;           // exact
    const unsigned short b2 = f2bf(r2);
    h0[e] = b0; h1[e] = b1; h2[e] = b2;
  }
  const int kt = gi >> 2, s = gi & 3;
  char* base = reinterpret_cast<char*>(Bb);
  *reinterpret_cast<u16x8*>(base + ((size_t)((kt * 3 + 0) * 4 + s) * Nn + n) * 16) = h0;
  *reinterpret_cast<u16x8*>(base + ((size_t)((kt * 3 + 1) * 4 + s) * Nn + n) * 16) = h1;
  *reinterpret_cast<u16x8*>(base + ((size_t)((kt * 3 + 2) * 4 + s) * Nn + n) * 16) = h2;
}

// ---- Main GEMM + Izhikevich epilogue: 128x128, BK=32, 2-phase dbuf --------
__launch_bounds__(256, 2)
__global__ void gemm_spike(const char* __restrict__ Ab, const char* __restrict__ Bb,
                           const float* __restrict__ v0, const float* __restrict__ u0,
                           float* __restrict__ out) {
  // Double-buffered LDS: buf stride 32 KiB.
  //   buf b: A [s(4)][m(128)][16B] @ b*32768 ; B [p(3)][s(4)][n(128)][16B] @ b*32768+8192
  __shared__ __align__(16) char lds[65536];
  const int t = (int)threadIdx.x;
  // Bijective XCD swizzle (512 blocks, 64/XCD): A-slab sharers (same mt,
  // consecutive orig-bx) land on the same XCD's L2.
  const int bx0 = (int)blockIdx.x;
  const int bx  = (bx0 & 7) * 64 + (bx0 >> 3);
  const int mt = bx >> 2, nt = bx & 3;
  const int m0 = mt * BM, n0 = nt * BN;

  // staging source offsets (within current kt slab)
  uint32_t asrc[2], bsrc[6];
#pragma unroll
  for (int c = 0; c < 2; ++c) {
    const int j = t + 256 * c;          // 0..511 : s=j>>7, i=j&127
    asrc[c] = (uint32_t)((((j >> 7) * Bn) + m0 + (j & 127)) * 16);
  }
#pragma unroll
  for (int c = 0; c < 6; ++c) {
    const int j = t + 256 * c;          // 0..1535 : p=j>>9, s=(j>>7)&3, i=j&127
    bsrc[c] = (uint32_t)(((((j >> 9) * 4 + ((j >> 7) & 3)) * Nn) + n0 + (j & 127)) * 16);
  }

  const int l  = t & 63, wv = t >> 6;
  const int wr = wv >> 1, wc = wv & 1;  // wave grid 2(M) x 2(N), wave tile 64x64
  const int lr = l & 15, kh = l >> 4;

  uint32_t aoff[4], boff[3][4];
#pragma unroll
  for (int mf = 0; mf < 4; ++mf)
    aoff[mf] = (uint32_t)(((kh * 128) + wr * 64 + mf * 16 + lr) * 16);
#pragma unroll
  for (int p = 0; p < 3; ++p)
#pragma unroll
    for (int nf = 0; nf < 4; ++nf)
      boff[p][nf] = (uint32_t)(8192 + (((p * 4 + kh) * 128) + wc * 64 + nf * 16 + lr) * 16);

  f32x4 acc[4][4];
#pragma unroll
  for (int i = 0; i < 4; ++i)
#pragma unroll
    for (int j = 0; j < 4; ++j)
      acc[i][j] = (f32x4){0.0f, 0.0f, 0.0f, 0.0f};

  // ---- Prologue: stage tile 0 into buf 0 ----------------------------------
#pragma unroll
  for (int c = 0; c < 2; ++c) glds16(Ab + asrc[c], &lds[(t + 256 * c) * 16]);
#pragma unroll
  for (int c = 0; c < 6; ++c) glds16(Bb + bsrc[c], &lds[8192 + (t + 256 * c) * 16]);
  __syncthreads();   // compiler drains vmcnt(0) before s_barrier

  for (int kt = 0; kt < NKT; ++kt) {
    const int cb = (kt & 1) << 15;        // current buffer base
    // -- Phase A: issue next tile's staging FIRST (hides under compute) -----
    if (kt + 1 < NKT) {
      const int nb = ((kt + 1) & 1) << 15;
      const char* pa = Ab + (size_t)(kt + 1) * SLAB_A;
      const char* pb = Bb + (size_t)(kt + 1) * SLAB_B;
#pragma unroll
      for (int c = 0; c < 2; ++c) glds16(pa + asrc[c], &lds[nb + (t + 256 * c) * 16]);
#pragma unroll
      for (int c = 0; c < 6; ++c) glds16(pb + bsrc[c], &lds[nb + 8192 + (t + 256 * c) * 16]);
    }
    // -- Phase B: compute current buffer ------------------------------------
    bf16x8 af[4], bfr[3][4];
#pragma unroll
    for (int mf = 0; mf < 4; ++mf)
      af[mf] = *reinterpret_cast<const bf16x8*>(&lds[cb + aoff[mf]]);
#pragma unroll
    for (int p = 0; p < 3; ++p)
#pragma unroll
      for (int nf = 0; nf < 4; ++nf)
        bfr[p][nf] = *reinterpret_cast<const bf16x8*>(&lds[cb + boff[p][nf]]);
#pragma unroll
    for (int p = 0; p < 3; ++p)
#pragma unroll
      for (int mf = 0; mf < 4; ++mf)
#pragma unroll
        for (int nf = 0; nf < 4; ++nf)
          acc[mf][nf] = __builtin_amdgcn_mfma_f32_16x16x32_bf16(
              af[mf], bfr[p][nf], acc[mf][nf], 0, 0, 0);
    // -- ONE barrier per K-step: drains vmcnt (next tile staged) and closes
    //    this buffer's reads before it is overwritten two iters later. ------
    __syncthreads();
  }

  // epilogue: C/D layout (16x16): col = lane&15, row = (lane>>4)*4 + reg
#pragma unroll
  for (int nf = 0; nf < 4; ++nf) {
    const int ncol = n0 + wc * 64 + nf * 16 + lr;
    const float vi = v0[ncol], ui = u0[ncol];
#pragma unroll
    for (int mf = 0; mf < 4; ++mf) {
      const int mrow = m0 + wr * 64 + mf * 16 + kh * 4;
#pragma unroll
      for (int r = 0; r < 4; ++r) {
        const float I = acc[mf][nf][r] * 10.0f;
        out[(size_t)(mrow + r) * Nn + ncol] = izhi5(I, vi, ui);
      }
    }
  }
}

// ---- Fallback (round-1 exact sparse kernel) if ws too small ---------------
constexpr int ROWS = 32, TG = 16, NCHUNK = Gn / 32;

__launch_bounds__(512, 2)
__global__ void ca3_sparse_kernel(const float* __restrict__ dg,
                                  const float* __restrict__ Wm,
                                  const float* __restrict__ v0,
                                  const float* __restrict__ u0,
                                  float* __restrict__ out) {
#pragma clang fp contract(off)
  __shared__ float    lds_w[TG * Nn];
  __shared__ uint32_t lds_bits[ROWS][NCHUNK];
  const int t    = (int)threadIdx.x;
  const int row0 = (int)blockIdx.x * ROWS;
  {
    const int r  = t >> 4;
    const int c0 = (t & 15) * 4;
    const float* p = dg + (size_t)(row0 + r) * Gn + (size_t)c0 * 32;
#pragma unroll
    for (int cc = 0; cc < 4; ++cc) {
      uint32_t bits = 0;
#pragma unroll
      for (int i = 0; i < 8; ++i) {
        float4 x = reinterpret_cast<const float4*>(p + cc * 32)[i];
        bits |= (x.x != 0.0f ? 1u : 0u) << (i * 4 + 0);
        bits |= (x.y != 0.0f ? 1u : 0u) << (i * 4 + 1);
        bits |= (x.z != 0.0f ? 1u : 0u) << (i * 4 + 2);
        bits |= (x.w != 0.0f ? 1u : 0u) << (i * 4 + 3);
      }
      lds_bits[r][c0 + cc] = bits;
    }
  }
  float acc[ROWS];
#pragma unroll
  for (int r = 0; r < ROWS; ++r) acc[r] = 0.0f;
  for (int gt = 0; gt < Gn / TG; ++gt) {
    __syncthreads();
    {
      const int k  = t & 3;
      const int nb = t >> 2;
#pragma unroll
      for (int pq = 0; pq < 4; ++pq) {
        const int n = pq * 128 + nb;
        const float4 w4 = *reinterpret_cast<const float4*>(
            Wm + (size_t)n * Gn + gt * TG + k * 4);
        lds_w[(k * 4 + 0) * Nn + n] = w4.x;
        lds_w[(k * 4 + 1) * Nn + n] = w4.y;
        lds_w[(k * 4 + 2) * Nn + n] = w4.z;
        lds_w[(k * 4 + 3) * Nn + n] = w4.w;
      }
    }
    __syncthreads();
    const int shift = (gt & 1) * 16;
#pragma unroll
    for (int r = 0; r < ROWS; ++r) {
      uint32_t b = (lds_bits[r][gt >> 1] >> shift) & 0xFFFFu;
      b = __builtin_amdgcn_readfirstlane(b);
      while (b) {
        const int g0 = __builtin_ctz(b);
        const uint32_t b1 = b & (b - 1);
        const int g1 = __builtin_ctz(b1 | 0x8000u);
        const uint32_t b2 = b1 & (b1 - 1);
        const int g2 = __builtin_ctz(b2 | 0x8000u);
        const uint32_t b3 = b2 & (b2 - 1);
        const int g3 = __builtin_ctz(b3 | 0x8000u);
        float x0 = lds_w[g0 * Nn + t];
        float x1 = lds_w[g1 * Nn + t];
        float x2 = lds_w[g2 * Nn + t];
        float x3 = lds_w[g3 * Nn + t];
        x1 = (b1 != 0u) ? x1 : 0.0f;
        x2 = (b2 != 0u) ? x2 : 0.0f;
        x3 = (b3 != 0u) ? x3 : 0.0f;
        acc[r] += x0; acc[r] += x1; acc[r] += x2; acc[r] += x3;
        b = b3 & (b3 - 1);
      }
    }
  }
  const float vi = v0[t];
  const float ui = u0[t];
#pragma unroll
  for (int r = 0; r < ROWS; ++r) {
    out[(size_t)(row0 + r) * Nn + t] = izhi5(acc[r] * 10.0f, vi, ui);
  }
}

extern "C" void kernel_launch(void* const* d_in, const int* in_sizes, int n_in,
                              void* d_out, int out_size, void* d_ws, size_t ws_size,
                              hipStream_t stream) {
  const float* dg = (const float*)d_in[0];
  const float* Wm = (const float*)d_in[1];
  const float* v0 = (const float*)d_in[3];
  const float* u0 = (const float*)d_in[4];
  float* out = (float*)d_out;

  if (ws_size < A_BYTES + B_BYTES) {
    hipLaunchKernelGGL(ca3_sparse_kernel, dim3(Bn / ROWS), dim3(512), 0, stream,
                       dg, Wm, v0, u0, out);
    return;
  }
  char* Ab = (char*)d_ws;
  char* Bb = (char*)d_ws + A_BYTES;
  hipLaunchKernelGGL(prep_dg, dim3(2048), dim3(256), 0, stream,
                     dg, (unsigned short*)Ab);
  hipLaunchKernelGGL(prep_W, dim3(512), dim3(256), 0, stream,
                     Wm, (unsigned short*)Bb);
  hipLaunchKernelGGL(gemm_spike, dim3(512), dim3(256), 0, stream,
                     Ab, Bb, v0, u0, out);
}